// Round 5
// baseline (505.224 us; speedup 1.0000x reference)
//
#include <hip/hip_runtime.h>
#include <hip/hip_bf16.h>

#define B 512
#define N 1024
#define D 1024
#define FUSE 1024
#define A 256

typedef float f32x4 __attribute__((ext_vector_type(4)));
typedef short bf16x8 __attribute__((ext_vector_type(8)));
typedef unsigned short u16x4 __attribute__((ext_vector_type(4)));

__device__ __forceinline__ float fast_exp2(float x) { return __builtin_amdgcn_exp2f(x); }
__device__ __forceinline__ float fast_rcp(float x)  { return __builtin_amdgcn_rcpf(x); }

static constexpr float TANH_C = 2.8853900817779268f; // 2*log2(e)
static constexpr float LOG2E  = 1.4426950408889634f;

__device__ __forceinline__ unsigned short f2bf(float x) {
    __hip_bfloat16 h = __float2bfloat16(x);
    return *reinterpret_cast<unsigned short*>(&h);
}

// --- LDS union: one 32 KB arena shared by all phases ---
struct SMemGemm  { char As[16384]; char Bs[16384]; };
struct SMemSc    { f32x4 qs[32 * 32]; f32x4 ks[32 * 32]; };
union SMem {
    float castTile[64 * 65];   // 16.6 KB
    SMemGemm g;                // 32 KB
    SMemSc   sc;               // 32 KB
    float red[8];
};

// --- device-scope grid barrier: monotonic counter, all 512 blocks arrive ---
__device__ __forceinline__ void grid_barrier(unsigned* bar, unsigned target) {
    __syncthreads();
    __threadfence();                       // release this block's global writes
    if (threadIdx.x == 0) {
        atomicAdd(bar, 1u);
        while (atomicAdd(bar, 0u) < target) __builtin_amdgcn_s_sleep(4);
    }
    __syncthreads();
    __threadfence();                       // acquire other blocks' writes
}

// ---------------------------------------------------------------------------
// 64x64-tile bf16 MFMA GEMM, 2-phase double-buffered global_load_lds pipeline.
// LDS per tile: [64 rows][128 B], XOR-swizzled byte ^= ((row&7)<<4), applied
// by pre-swizzling the SOURCE address (LDS dest linear, rule #21).
// ---------------------------------------------------------------------------
__device__ __forceinline__ void gemm64_pipe(
    const short* __restrict__ Ag, const short* __restrict__ Btg,
    float* __restrict__ C, int lda, int Klen, int ldc, int m0, int n0,
    char* As, char* Bs)
{
    const int tid = threadIdx.x;
    const int w = tid >> 6, l = tid & 63;
    const int wm = w >> 1, wn = w & 1;
    const int lr = l & 15;
    const int cr = (l >> 4) * 4;
    const int rsub = l >> 3;
    const int ssrc = ((l & 7) ^ rsub) << 3;   // pre-swizzled src offset (shorts)

    auto stage = [&](int buf, int k0) {
#pragma unroll
        for (int p = 0; p < 2; ++p) {
            int chunk = (w << 1) | p;
            int row = (chunk << 3) | rsub;
            int ldsoff = (buf << 13) | (chunk << 10);
            __builtin_amdgcn_global_load_lds(
                (const __attribute__((address_space(1))) unsigned int*)
                    (Ag + (size_t)(m0 + row) * lda + k0 + ssrc),
                (__attribute__((address_space(3))) unsigned int*)(As + ldsoff),
                16, 0, 0);
            __builtin_amdgcn_global_load_lds(
                (const __attribute__((address_space(1))) unsigned int*)
                    (Btg + (size_t)(n0 + row) * lda + k0 + ssrc),
                (__attribute__((address_space(3))) unsigned int*)(Bs + ldsoff),
                16, 0, 0);
        }
    };

    f32x4 acc[2][2] = {};
    const int nt = Klen >> 6;

    stage(0, 0);
    asm volatile("s_waitcnt vmcnt(0)" ::: "memory");
    __builtin_amdgcn_s_barrier();

    int cur = 0;
    for (int t = 0; t < nt; ++t) {
        if (t + 1 < nt) stage(cur ^ 1, (t + 1) << 6);

        const char* Ab = As + (cur << 13);
        const char* Bb = Bs + (cur << 13);
        bf16x8 af[2][2], bq[2][2];
#pragma unroll
        for (int ks = 0; ks < 2; ++ks)
#pragma unroll
            for (int i = 0; i < 2; ++i) {
                int j = ks * 64 + ((l >> 4) << 4);
                int r = wm * 32 + i * 16 + lr;
                af[i][ks] = *(const bf16x8*)(Ab + r * 128 + (j ^ ((r & 7) << 4)));
                int c = wn * 32 + i * 16 + lr;
                bq[i][ks] = *(const bf16x8*)(Bb + c * 128 + (j ^ ((c & 7) << 4)));
            }
#pragma unroll
        for (int ks = 0; ks < 2; ++ks)
#pragma unroll
            for (int am = 0; am < 2; ++am)
#pragma unroll
                for (int bn = 0; bn < 2; ++bn)
                    acc[am][bn] = __builtin_amdgcn_mfma_f32_16x16x32_bf16(
                        af[am][ks], bq[bn][ks], acc[am][bn], 0, 0, 0);

        asm volatile("s_waitcnt vmcnt(0)" ::: "memory");
        __builtin_amdgcn_s_barrier();
        cur ^= 1;
    }

#pragma unroll
    for (int am = 0; am < 2; ++am)
#pragma unroll
        for (int bn = 0; bn < 2; ++bn) {
            float* cp = C + (size_t)(m0 + wm * 32 + am * 16 + cr) * ldc
                          + n0 + wn * 32 + bn * 16 + lr;
#pragma unroll
            for (int r = 0; r < 4; ++r) cp[(size_t)r * ldc] = acc[am][bn][r];
        }
}

// ---------------------------------------------------------------------------
// Mega-kernel: 512 blocks x 256 threads, 5 phases + 4 grid barriers.
// ---------------------------------------------------------------------------
__global__ __launch_bounds__(256, 2) void mega_kernel(
    const float* __restrict__ conf, const float* __restrict__ fuse,
    const float* __restrict__ probs,
    const float* __restrict__ Wq, const float* __restrict__ Wk,
    const float* __restrict__ wt,
    float* __restrict__ out,
    short* __restrict__ fuse_bf, short* __restrict__ conf_bf,
    short* __restrict__ confT, short* __restrict__ WqT, short* __restrict__ WkT,
    float* __restrict__ qpart, float* __restrict__ kpart,
    float* __restrict__ sbuf, short* __restrict__ wbuf,
    unsigned* __restrict__ bar)
{
    __shared__ SMem smem;
    const int bid = blockIdx.x;
    const int tid = threadIdx.x;

    // ------------------ Phase 0: cast (+prescale W by TANH_C) ------------------
    {
        const float* src; short* dstS = nullptr; short* dstT = nullptr;
        int r0, c0, spitch; float scale = 1.0f;
        if (bid < 128) {
            src = fuse; dstS = fuse_bf; spitch = FUSE;
            r0 = (bid >> 4) * 64; c0 = (bid & 15) * 64;
        } else if (bid < 384) {
            int b = bid - 128; src = conf; dstS = conf_bf; dstT = confT; spitch = D;
            r0 = (b >> 4) * 64; c0 = (b & 15) * 64;
        } else if (bid < 448) {
            int b = bid - 384; src = Wq; dstT = WqT; spitch = A; scale = TANH_C;
            r0 = (b >> 2) * 64; c0 = (b & 3) * 64;
        } else {
            int b = bid - 448; src = Wk; dstT = WkT; spitch = A; scale = TANH_C;
            r0 = (b >> 2) * 64; c0 = (b & 3) * 64;
        }
        const int tr = tid >> 4, tc = (tid & 15) * 4;
        f32x4 v[4];
#pragma unroll
        for (int i = 0; i < 4; ++i) {
            v[i] = *(const f32x4*)(src + (size_t)(r0 + tr + 16 * i) * spitch + c0 + tc);
#pragma unroll
            for (int j = 0; j < 4; ++j) v[i][j] *= scale;
        }
        if (dstS) {
#pragma unroll
            for (int i = 0; i < 4; ++i) {
                u16x4 o;
#pragma unroll
                for (int j = 0; j < 4; ++j) o[j] = f2bf(v[i][j]);
                *(u16x4*)(dstS + (size_t)(r0 + tr + 16 * i) * spitch + c0 + tc) = o;
            }
        }
        if (dstT) {
#pragma unroll
            for (int i = 0; i < 4; ++i)
#pragma unroll
                for (int j = 0; j < 4; ++j)
                    smem.castTile[(tr + 16 * i) * 65 + tc + j] = v[i][j];
            __syncthreads();
#pragma unroll
            for (int i = 0; i < 4; ++i) {
                int orow = tr + 16 * i;
                u16x4 o;
#pragma unroll
                for (int j = 0; j < 4; ++j) o[j] = f2bf(smem.castTile[(tc + j) * 65 + orow]);
                *(u16x4*)(dstT + (size_t)(c0 + orow) * 1024 + r0 + tc) = o;
            }
        }
    }
    grid_barrier(bar, 512);

    // ------------------ Phase 1: qk projection GEMMs (K-split 2) ---------------
    if (bid < 192) {
        int khalf = (bid >= 96) ? 1 : 0;
        int tile = bid - khalf * 96;
        const short* Aop; const short* Bop; float* Cp; int m0, n0;
        if (tile < 32) {
            Aop = fuse_bf; Bop = WqT; Cp = qpart + (size_t)khalf * B * A;
            m0 = (tile >> 2) * 64; n0 = (tile & 3) * 64;
        } else {
            int t2 = tile - 32;
            Aop = conf_bf; Bop = WkT; Cp = kpart + (size_t)khalf * N * A;
            m0 = (t2 >> 2) * 64; n0 = (t2 & 3) * 64;
        }
        gemm64_pipe(Aop + khalf * 512, Bop + khalf * 512, Cp,
                    1024, 512, A, m0, n0, smem.g.As, smem.g.Bs);
    }
    grid_barrier(bar, 1024);

    // ------------------ Phase 2: scores (A in 2 chunks of 128) -----------------
    {
        const int b0 = (bid & 15) * 32;
        const int n0 = (bid >> 4) * 32;
        const f32x4* qp0 = (const f32x4*)qpart;
        const f32x4* qp1 = qp0 + (size_t)B * A / 4;
        const f32x4* kp0 = (const f32x4*)kpart;
        const f32x4* kp1 = kp0 + (size_t)N * A / 4;
        const f32x4* wt4 = (const f32x4*)wt;
        const int bl = tid >> 5;    // 0..7
        const int nl = tid & 31;    // 0..31

        float acc0 = 0.f, acc1 = 0.f, acc2 = 0.f, acc3 = 0.f;
#pragma unroll
        for (int c = 0; c < 2; ++c) {
#pragma unroll
            for (int j = 0; j < 4; ++j) {
                int idx = tid + j * 256;
                int r = idx >> 5, col = idx & 31;
                size_t qsrc = (size_t)(b0 + r) * 64 + c * 32 + col;
                size_t ksrc = (size_t)(n0 + r) * 64 + c * 32 + col;
                smem.sc.qs[r * 32 + col] = qp0[qsrc] + qp1[qsrc];
                smem.sc.ks[r * 32 + (col ^ (r & 15))] = kp0[ksrc] + kp1[ksrc];
            }
            __syncthreads();
            for (int a4 = 0; a4 < 32; ++a4) {
                f32x4 kv = smem.sc.ks[nl * 32 + (a4 ^ (nl & 15))];
                f32x4 wv = wt4[c * 32 + a4];
                f32x4 q0 = smem.sc.qs[(bl) * 32 + a4];
                f32x4 q1 = smem.sc.qs[(bl + 8) * 32 + a4];
                f32x4 q2 = smem.sc.qs[(bl + 16) * 32 + a4];
                f32x4 q3 = smem.sc.qs[(bl + 24) * 32 + a4];
#pragma unroll
                for (int cc = 0; cc < 4; ++cc) {
                    float kc = kv[cc], wc = wv[cc];
                    acc0 += wc * fast_rcp(fast_exp2(q0[cc] + kc) + 1.0f);
                    acc1 += wc * fast_rcp(fast_exp2(q1[cc] + kc) + 1.0f);
                    acc2 += wc * fast_rcp(fast_exp2(q2[cc] + kc) + 1.0f);
                    acc3 += wc * fast_rcp(fast_exp2(q3[cc] + kc) + 1.0f);
                }
            }
            __syncthreads();
        }
        sbuf[(size_t)(b0 + bl) * N + n0 + nl]      = -2.0f * acc0;
        sbuf[(size_t)(b0 + bl + 8) * N + n0 + nl]  = -2.0f * acc1;
        sbuf[(size_t)(b0 + bl + 16) * N + n0 + nl] = -2.0f * acc2;
        sbuf[(size_t)(b0 + bl + 24) * N + n0 + nl] = -2.0f * acc3;
    }
    grid_barrier(bar, 1536);

    // ------------------ Phase 3: softmax x probs -> bf16 weights ---------------
    {
        const int b = bid;
        const f32x4* s4 = (const f32x4*)(sbuf + (size_t)b * N);
        f32x4 v = s4[tid];
        float m = fmaxf(fmaxf(v[0], v[1]), fmaxf(v[2], v[3]));
        for (int off = 32; off > 0; off >>= 1) m = fmaxf(m, __shfl_xor(m, off));
        const int wid = tid >> 6, lane = tid & 63;
        if (lane == 0) smem.red[wid] = m;
        __syncthreads();
        m = fmaxf(fmaxf(smem.red[0], smem.red[1]), fmaxf(smem.red[2], smem.red[3]));

        f32x4 e;
#pragma unroll
        for (int c = 0; c < 4; ++c) e[c] = fast_exp2((v[c] - m) * LOG2E);
        float sum = e[0] + e[1] + e[2] + e[3];
        for (int off = 32; off > 0; off >>= 1) sum += __shfl_xor(sum, off);
        __syncthreads();   // red[] reuse
        if (lane == 0) smem.red[4 + wid] = sum;
        __syncthreads();
        sum = smem.red[4] + smem.red[5] + smem.red[6] + smem.red[7];

        const float inv = fast_rcp(sum);
        const f32x4* p4 = (const f32x4*)probs;
        f32x4 p = p4[tid];
        u16x4 o;
#pragma unroll
        for (int c = 0; c < 4; ++c) o[c] = f2bf(e[c] * inv * p[c]);
        ((u16x4*)(wbuf + (size_t)b * N))[tid] = o;
    }
    grid_barrier(bar, 2048);

    // ------------------ Phase 4: fin = w_bf @ confT^T --------------------------
    if (bid < 128) {
        int x = bid & 15, y = bid >> 4;
        gemm64_pipe(wbuf, confT, out, 1024, 1024, D, y * 64, x * 64,
                    smem.g.As, smem.g.Bs);
    }
}

// ---------------------------------------------------------------------------
extern "C" void kernel_launch(void* const* d_in, const int* in_sizes, int n_in,
                              void* d_out, int out_size, void* d_ws, size_t ws_size,
                              hipStream_t stream) {
    const float* conf     = (const float*)d_in[0]; // [N,D]
    const float* fuse_rep = (const float*)d_in[1]; // [B,FUSE]
    const float* probs    = (const float*)d_in[2]; // [1,N]
    const float* Wq       = (const float*)d_in[3]; // [FUSE,A]
    const float* Wk       = (const float*)d_in[4]; // [D,A]
    const float* wt       = (const float*)d_in[5]; // [A]
    float* out = (float*)d_out;                    // [B,D]

    char* w = (char*)d_ws;
    float* qpart  = (float*)(w);                    // 2 x 512 KB   @ 0
    float* kpart  = (float*)(w + (1u << 20));       // 2 x 1 MB     @ 1M
    float* sbuf   = (float*)(w + (3u << 20));       // 2 MB         @ 3M
    short* fuse_bf= (short*)(w + (5u << 20));       // 1 MB         @ 5M
    short* conf_bf= (short*)(w + (6u << 20));       // 2 MB         @ 6M
    short* confT  = (short*)(w + (8u << 20));       // 2 MB         @ 8M
    short* WqT    = (short*)(w + (10u << 20));      // 512 KB       @ 10M
    short* WkT    = (short*)(w + (10u << 20) + (512u << 10)); // 512 KB
    short* wbuf   = (short*)(w + (11u << 20));      // 1 MB         @ 11M
    unsigned* bar = (unsigned*)(w + (12u << 20));   // 4 B          @ 12M

    hipMemsetAsync(bar, 0, sizeof(unsigned), stream);
    hipLaunchKernelGGL(mega_kernel, dim3(512), dim3(256), 0, stream,
                       conf, fuse_rep, probs, Wq, Wk, wt, out,
                       fuse_bf, conf_bf, confT, WqT, WkT,
                       qpart, kpart, sbuf, wbuf, bar);
}

// Round 6
// 124.039 us; speedup vs baseline: 4.0731x; 4.0731x over previous
//
#include <hip/hip_runtime.h>
#include <hip/hip_bf16.h>

#define B 512
#define N 1024
#define D 1024
#define FUSE 1024
#define A 256

typedef float f32x4 __attribute__((ext_vector_type(4)));
typedef short bf16x8 __attribute__((ext_vector_type(8)));
typedef unsigned short u16x4 __attribute__((ext_vector_type(4)));

__device__ __forceinline__ float fast_exp2(float x) { return __builtin_amdgcn_exp2f(x); }
__device__ __forceinline__ float fast_rcp(float x)  { return __builtin_amdgcn_rcpf(x); }

static constexpr float TANH_C = 2.8853900817779268f; // 2*log2(e)
static constexpr float LOG2E  = 1.4426950408889634f;

__device__ __forceinline__ unsigned short f2bf(float x) {
    __hip_bfloat16 h = __float2bfloat16(x);
    return *reinterpret_cast<unsigned short*>(&h);
}

// ---------------------------------------------------------------------------
// Kernel 0: cast inputs to bf16. Straight: fuse_rep, conf. Transposed (so the
// GEMM B-operand is K-contiguous): conf^T, (Wq*TANH_C)^T, (Wk*TANH_C)^T.
// ---------------------------------------------------------------------------
__global__ __launch_bounds__(256) void cast_kernel(
    const float* __restrict__ fuse, const float* __restrict__ conf,
    const float* __restrict__ Wq, const float* __restrict__ Wk,
    short* __restrict__ fuse_bf, short* __restrict__ conf_bf,
    short* __restrict__ confT, short* __restrict__ WqT, short* __restrict__ WkT)
{
    __shared__ float tile[64 * 65];
    int bid = blockIdx.x;
    const float* src; short* dstS = nullptr; short* dstT = nullptr;
    int r0, c0, spitch; float scale = 1.0f;
    if (bid < 128) {
        src = fuse; dstS = fuse_bf; spitch = FUSE;
        r0 = (bid >> 4) * 64; c0 = (bid & 15) * 64;
    } else if (bid < 384) {
        int b = bid - 128; src = conf; dstS = conf_bf; dstT = confT; spitch = D;
        r0 = (b >> 4) * 64; c0 = (b & 15) * 64;
    } else if (bid < 448) {
        int b = bid - 384; src = Wq; dstT = WqT; spitch = A; scale = TANH_C;
        r0 = (b >> 2) * 64; c0 = (b & 3) * 64;
    } else {
        int b = bid - 448; src = Wk; dstT = WkT; spitch = A; scale = TANH_C;
        r0 = (b >> 2) * 64; c0 = (b & 3) * 64;
    }
    const int tr = threadIdx.x >> 4, tc = (threadIdx.x & 15) * 4;

    f32x4 v[4];
#pragma unroll
    for (int i = 0; i < 4; ++i) {
        v[i] = *(const f32x4*)(src + (size_t)(r0 + tr + 16 * i) * spitch + c0 + tc);
#pragma unroll
        for (int j = 0; j < 4; ++j) v[i][j] *= scale;
    }
    if (dstS) {
#pragma unroll
        for (int i = 0; i < 4; ++i) {
            u16x4 o;
#pragma unroll
            for (int j = 0; j < 4; ++j) o[j] = f2bf(v[i][j]);
            *(u16x4*)(dstS + (size_t)(r0 + tr + 16 * i) * spitch + c0 + tc) = o;
        }
    }
    if (dstT) {
#pragma unroll
        for (int i = 0; i < 4; ++i)
#pragma unroll
            for (int j = 0; j < 4; ++j) tile[(tr + 16 * i) * 65 + tc + j] = v[i][j];
        __syncthreads();
#pragma unroll
        for (int i = 0; i < 4; ++i) {
            int orow = tr + 16 * i;
            u16x4 o;
#pragma unroll
            for (int j = 0; j < 4; ++j) o[j] = f2bf(tile[(tc + j) * 65 + orow]);
            *(u16x4*)(dstT + (size_t)(c0 + orow) * 1024 + r0 + tc) = o;
        }
    }
}

// ---------------------------------------------------------------------------
// 64x64-tile bf16 MFMA GEMM, 2-phase double-buffered global_load_lds pipeline.
// LDS per tile: [64 rows][128 B], XOR-swizzled byte ^= ((row&7)<<4), applied
// by pre-swizzling the SOURCE address (LDS dest linear, rule #21).
// ---------------------------------------------------------------------------
__device__ __forceinline__ void gemm64_pipe(
    const short* __restrict__ Ag, const short* __restrict__ Btg,
    float* __restrict__ C, int lda, int Klen, int ldc, int m0, int n0,
    char* As, char* Bs)
{
    const int tid = threadIdx.x;
    const int w = tid >> 6, l = tid & 63;
    const int wm = w >> 1, wn = w & 1;
    const int lr = l & 15;
    const int cr = (l >> 4) * 4;
    const int rsub = l >> 3;
    const int ssrc = ((l & 7) ^ rsub) << 3;   // pre-swizzled src offset (shorts)

    auto stage = [&](int buf, int k0) {
#pragma unroll
        for (int p = 0; p < 2; ++p) {
            int chunk = (w << 1) | p;
            int row = (chunk << 3) | rsub;
            int ldsoff = (buf << 13) | (chunk << 10);
            __builtin_amdgcn_global_load_lds(
                (const __attribute__((address_space(1))) unsigned int*)
                    (Ag + (size_t)(m0 + row) * lda + k0 + ssrc),
                (__attribute__((address_space(3))) unsigned int*)(As + ldsoff),
                16, 0, 0);
            __builtin_amdgcn_global_load_lds(
                (const __attribute__((address_space(1))) unsigned int*)
                    (Btg + (size_t)(n0 + row) * lda + k0 + ssrc),
                (__attribute__((address_space(3))) unsigned int*)(Bs + ldsoff),
                16, 0, 0);
        }
    };

    f32x4 acc[2][2] = {};
    const int nt = Klen >> 6;

    stage(0, 0);
    asm volatile("s_waitcnt vmcnt(0)" ::: "memory");
    __builtin_amdgcn_s_barrier();

    int cur = 0;
    for (int t = 0; t < nt; ++t) {
        if (t + 1 < nt) stage(cur ^ 1, (t + 1) << 6);

        const char* Ab = As + (cur << 13);
        const char* Bb = Bs + (cur << 13);
        bf16x8 af[2][2], bq[2][2];
#pragma unroll
        for (int ks = 0; ks < 2; ++ks)
#pragma unroll
            for (int i = 0; i < 2; ++i) {
                int j = ks * 64 + ((l >> 4) << 4);
                int r = wm * 32 + i * 16 + lr;
                af[i][ks] = *(const bf16x8*)(Ab + r * 128 + (j ^ ((r & 7) << 4)));
                int c = wn * 32 + i * 16 + lr;
                bq[i][ks] = *(const bf16x8*)(Bb + c * 128 + (j ^ ((c & 7) << 4)));
            }
#pragma unroll
        for (int ks = 0; ks < 2; ++ks)
#pragma unroll
            for (int am = 0; am < 2; ++am)
#pragma unroll
                for (int bn = 0; bn < 2; ++bn)
                    acc[am][bn] = __builtin_amdgcn_mfma_f32_16x16x32_bf16(
                        af[am][ks], bq[bn][ks], acc[am][bn], 0, 0, 0);

        asm volatile("s_waitcnt vmcnt(0)" ::: "memory");
        __builtin_amdgcn_s_barrier();
        cur ^= 1;
    }

#pragma unroll
    for (int am = 0; am < 2; ++am)
#pragma unroll
        for (int bn = 0; bn < 2; ++bn) {
            float* cp = C + (size_t)(m0 + wm * 32 + am * 16 + cr) * ldc
                          + n0 + wn * 32 + bn * 16 + lr;
#pragma unroll
            for (int r = 0; r < 4; ++r) cp[(size_t)r * ldc] = acc[am][bn][r];
        }
}

// Kernel 1: q/k projections, K-split 2 (192 blocks), partials to qpart/kpart.
__global__ __launch_bounds__(256) void qk_gemm_kernel(
    const short* __restrict__ fuse_bf, const short* __restrict__ conf_bf,
    const short* __restrict__ WqT, const short* __restrict__ WkT,
    float* __restrict__ qpart, float* __restrict__ kpart)
{
    __shared__ char As[16384];
    __shared__ char Bs[16384];
    int bid = blockIdx.x;
    int khalf = (bid >= 96) ? 1 : 0;
    int tile = bid - khalf * 96;
    const short* Aop; const short* Bop; float* Cp; int m0, n0;
    if (tile < 32) {
        Aop = fuse_bf; Bop = WqT; Cp = qpart + (size_t)khalf * B * A;
        m0 = (tile >> 2) * 64; n0 = (tile & 3) * 64;
    } else {
        int t2 = tile - 32;
        Aop = conf_bf; Bop = WkT; Cp = kpart + (size_t)khalf * N * A;
        m0 = (t2 >> 2) * 64; n0 = (t2 & 3) * 64;
    }
    gemm64_pipe(Aop + khalf * 512, Bop + khalf * 512, Cp,
                1024, 512, A, m0, n0, As, Bs);
}

// ---------------------------------------------------------------------------
// Kernel 4: fin = w_bf @ confT^T, 32(b) x 64(d) tiles -> 256 blocks, full K.
// Wave w: rows wm*16, cols wn*32 (2 B-frags). Same swizzle scheme as gemm64.
// ---------------------------------------------------------------------------
__global__ __launch_bounds__(256) void fin_gemm_kernel(
    const short* __restrict__ wb, const short* __restrict__ confT,
    float* __restrict__ out)
{
    __shared__ char As[8192];    // 2 buf x 32 rows x 128 B
    __shared__ char Bs[16384];   // 2 buf x 64 rows x 128 B
    const int b0 = blockIdx.y * 32, d0 = blockIdx.x * 64;
    const int tid = threadIdx.x;
    const int w = tid >> 6, l = tid & 63;
    const int wm = w >> 1, wn = w & 1;
    const int lr = l & 15;
    const int cr = (l >> 4) * 4;
    const int rsub = l >> 3;
    const int ssrc = ((l & 7) ^ rsub) << 3;

    auto stage = [&](int buf, int k0) {
        {   // A: 4 chunks, one per wave
            int row = (w << 3) | rsub;
            __builtin_amdgcn_global_load_lds(
                (const __attribute__((address_space(1))) unsigned int*)
                    (wb + (size_t)(b0 + row) * 1024 + k0 + ssrc),
                (__attribute__((address_space(3))) unsigned int*)(As + (buf << 12) + (w << 10)),
                16, 0, 0);
        }
#pragma unroll
        for (int p = 0; p < 2; ++p) {   // B: 8 chunks, two per wave
            int chunk = (w << 1) | p;
            int row = (chunk << 3) | rsub;
            __builtin_amdgcn_global_load_lds(
                (const __attribute__((address_space(1))) unsigned int*)
                    (confT + (size_t)(d0 + row) * 1024 + k0 + ssrc),
                (__attribute__((address_space(3))) unsigned int*)(Bs + (buf << 13) + (chunk << 10)),
                16, 0, 0);
        }
    };

    f32x4 acc[2] = {};
    stage(0, 0);
    asm volatile("s_waitcnt vmcnt(0)" ::: "memory");
    __builtin_amdgcn_s_barrier();

    int cur = 0;
    for (int t = 0; t < 16; ++t) {
        if (t < 15) stage(cur ^ 1, (t + 1) << 6);

        const char* Ab = As + (cur << 12);
        const char* Bb = Bs + (cur << 13);
#pragma unroll
        for (int ks = 0; ks < 2; ++ks) {
            int j = ks * 64 + ((l >> 4) << 4);
            int r = wm * 16 + lr;
            bf16x8 af = *(const bf16x8*)(Ab + r * 128 + (j ^ ((r & 7) << 4)));
#pragma unroll
            for (int i = 0; i < 2; ++i) {
                int c = wn * 32 + i * 16 + lr;
                bf16x8 bq = *(const bf16x8*)(Bb + c * 128 + (j ^ ((c & 7) << 4)));
                acc[i] = __builtin_amdgcn_mfma_f32_16x16x32_bf16(af, bq, acc[i], 0, 0, 0);
            }
        }
        asm volatile("s_waitcnt vmcnt(0)" ::: "memory");
        __builtin_amdgcn_s_barrier();
        cur ^= 1;
    }

#pragma unroll
    for (int i = 0; i < 2; ++i) {
        float* cp = out + (size_t)(b0 + wm * 16 + cr) * D + d0 + wn * 32 + i * 16 + lr;
#pragma unroll
        for (int r = 0; r < 4; ++r) cp[(size_t)r * D] = acc[i][r];
    }
}

// ---------------------------------------------------------------------------
// Kernel 2: scores, A in 2 chunks of 128 (32 KB LDS -> ~5 blocks/CU).
// Sums the 2 K-split partials during staging.
// ---------------------------------------------------------------------------
__global__ __launch_bounds__(256) void scores_kernel(
    const float* __restrict__ qpart, const float* __restrict__ kpart,
    const float* __restrict__ wt, float* __restrict__ sbuf)
{
    __shared__ f32x4 qs[32 * 32];
    __shared__ f32x4 ks[32 * 32];
    const int tid = threadIdx.x;
    const int bid = blockIdx.x;
    const int b0 = (bid & 15) * 32;
    const int n0 = (bid >> 4) * 32;

    const f32x4* qp0 = (const f32x4*)qpart;
    const f32x4* qp1 = qp0 + (size_t)B * A / 4;
    const f32x4* kp0 = (const f32x4*)kpart;
    const f32x4* kp1 = kp0 + (size_t)N * A / 4;
    const f32x4* wt4 = (const f32x4*)wt;
    const int bl = tid >> 5;    // 0..7
    const int nl = tid & 31;    // 0..31

    float acc0 = 0.f, acc1 = 0.f, acc2 = 0.f, acc3 = 0.f;
#pragma unroll
    for (int c = 0; c < 2; ++c) {
#pragma unroll
        for (int j = 0; j < 4; ++j) {
            int idx = tid + j * 256;
            int r = idx >> 5, col = idx & 31;
            size_t qsrc = (size_t)(b0 + r) * 64 + c * 32 + col;
            size_t ksrc = (size_t)(n0 + r) * 64 + c * 32 + col;
            qs[r * 32 + col] = qp0[qsrc] + qp1[qsrc];
            ks[r * 32 + (col ^ (r & 15))] = kp0[ksrc] + kp1[ksrc];
        }
        __syncthreads();
        for (int a4 = 0; a4 < 32; ++a4) {
            f32x4 kv = ks[nl * 32 + (a4 ^ (nl & 15))];
            f32x4 wv = wt4[c * 32 + a4];
            f32x4 q0 = qs[(bl) * 32 + a4];
            f32x4 q1 = qs[(bl + 8) * 32 + a4];
            f32x4 q2 = qs[(bl + 16) * 32 + a4];
            f32x4 q3 = qs[(bl + 24) * 32 + a4];
#pragma unroll
            for (int cc = 0; cc < 4; ++cc) {
                float kc = kv[cc], wc = wv[cc];
                acc0 += wc * fast_rcp(fast_exp2(q0[cc] + kc) + 1.0f);
                acc1 += wc * fast_rcp(fast_exp2(q1[cc] + kc) + 1.0f);
                acc2 += wc * fast_rcp(fast_exp2(q2[cc] + kc) + 1.0f);
                acc3 += wc * fast_rcp(fast_exp2(q3[cc] + kc) + 1.0f);
            }
        }
        __syncthreads();
    }
    sbuf[(size_t)(b0 + bl) * N + n0 + nl]      = -2.0f * acc0;
    sbuf[(size_t)(b0 + bl + 8) * N + n0 + nl]  = -2.0f * acc1;
    sbuf[(size_t)(b0 + bl + 16) * N + n0 + nl] = -2.0f * acc2;
    sbuf[(size_t)(b0 + bl + 24) * N + n0 + nl] = -2.0f * acc3;
}

// ---------------------------------------------------------------------------
// Kernel 3: row softmax over N, times probs[n]; emit bf16 attn weights.
// ---------------------------------------------------------------------------
__global__ __launch_bounds__(256) void softmax_kernel(
    const float* __restrict__ s, const float* __restrict__ probs,
    short* __restrict__ wbuf)
{
    const int b = blockIdx.x, tid = threadIdx.x;
    const f32x4* s4 = (const f32x4*)(s + (size_t)b * N);
    f32x4 v = s4[tid];

    float m = fmaxf(fmaxf(v[0], v[1]), fmaxf(v[2], v[3]));
    for (int off = 32; off > 0; off >>= 1) m = fmaxf(m, __shfl_xor(m, off));
    __shared__ float redm[4];
    __shared__ float reds[4];
    const int wid = tid >> 6, lane = tid & 63;
    if (lane == 0) redm[wid] = m;
    __syncthreads();
    m = fmaxf(fmaxf(redm[0], redm[1]), fmaxf(redm[2], redm[3]));

    f32x4 e;
#pragma unroll
    for (int c = 0; c < 4; ++c) e[c] = fast_exp2((v[c] - m) * LOG2E);
    float sum = e[0] + e[1] + e[2] + e[3];
    for (int off = 32; off > 0; off >>= 1) sum += __shfl_xor(sum, off);
    if (lane == 0) reds[wid] = sum;
    __syncthreads();
    sum = reds[0] + reds[1] + reds[2] + reds[3];

    const float inv = fast_rcp(sum);
    const f32x4* p4 = (const f32x4*)probs;
    f32x4 p = p4[tid];
    u16x4 o;
#pragma unroll
    for (int c = 0; c < 4; ++c) o[c] = f2bf(e[c] * inv * p[c]);
    ((u16x4*)(wbuf + (size_t)b * N))[tid] = o;
}

// ---------------------------------------------------------------------------
extern "C" void kernel_launch(void* const* d_in, const int* in_sizes, int n_in,
                              void* d_out, int out_size, void* d_ws, size_t ws_size,
                              hipStream_t stream) {
    const float* conf     = (const float*)d_in[0]; // [N,D]
    const float* fuse_rep = (const float*)d_in[1]; // [B,FUSE]
    const float* probs    = (const float*)d_in[2]; // [1,N]
    const float* Wq       = (const float*)d_in[3]; // [FUSE,A]
    const float* Wk       = (const float*)d_in[4]; // [D,A]
    const float* wt       = (const float*)d_in[5]; // [A]
    float* out = (float*)d_out;                    // [B,D]

    char* w = (char*)d_ws;
    float* qpart  = (float*)(w);                    // 2 x 512 KB  @ 0
    float* kpart  = (float*)(w + (1u << 20));       // 2 x 1 MB    @ 1M
    float* sbuf   = (float*)(w + (3u << 20));       // 2 MB        @ 3M
    short* fuse_bf= (short*)(w + (5u << 20));       // 1 MB        @ 5M
    short* conf_bf= (short*)(w + (6u << 20));       // 2 MB        @ 6M
    short* confT  = (short*)(w + (8u << 20));       // 2 MB        @ 8M
    short* WqT    = (short*)(w + (10u << 20));      // 512 KB      @ 10M
    short* WkT    = (short*)(w + (10u << 20) + (512u << 10)); // 512 KB
    short* wbuf   = (short*)(w + (11u << 20));      // 1 MB        @ 11M

    hipLaunchKernelGGL(cast_kernel, dim3(512), dim3(256), 0, stream,
                       fuse_rep, conf, Wq, Wk, fuse_bf, conf_bf, confT, WqT, WkT);
    hipLaunchKernelGGL(qk_gemm_kernel, dim3(192), dim3(256), 0, stream,
                       fuse_bf, conf_bf, WqT, WkT, qpart, kpart);
    hipLaunchKernelGGL(scores_kernel, dim3(512), dim3(256), 0, stream,
                       qpart, kpart, wt, sbuf);
    hipLaunchKernelGGL(softmax_kernel, dim3(B), dim3(256), 0, stream,
                       sbuf, probs, wbuf);
    hipLaunchKernelGGL(fin_gemm_kernel, dim3(D / 64, B / 32), dim3(256), 0, stream,
                       wbuf, confT, out);
}